// Round 12
// baseline (240.820 us; speedup 1.0000x reference)
//
#include <hip/hip_runtime.h>
#include <math.h>

#define N 1024
#define T 1024           // 16 waves: 4 per SIMD
#define HALF 512
#define PHASE_CAP 10
#define SWITCH 160       // switch to contracted Prim when comps <= SWITCH

typedef float v2f __attribute__((ext_vector_type(2)));
typedef unsigned long long ull;

#define INF64 0xFFFFFFFFFFFFFFFFull
#define INF32 0xFFFFFFFFu

__device__ __forceinline__ unsigned umin32(unsigned a, unsigned b) { return a < b ? a : b; }
__device__ __forceinline__ unsigned umax32(unsigned a, unsigned b) { return a > b ? a : b; }

// Root walk with 2-cycle detection (keys globally distinct => cycles are exactly
// mutual pairs; root = min of the pair). Safe under concurrent parent[x] <- root(x).
__device__ __forceinline__ unsigned walk_root(const unsigned* parent, unsigned x) {
    unsigned prev = x, cur = parent[x];
    while (cur != prev) {
        unsigned nxt = parent[cur];
        if (nxt == prev) { cur = umin32(cur, prev); break; }
        prev = cur; cur = nxt;
    }
    return cur;
}

// DPP row_shr min step (row = 16 lanes), identity = 0xFFFFFFFF
#define DPP_MIN_SHR(v, sh)                                                                   \
    do {                                                                                     \
        unsigned _t = (unsigned)__builtin_amdgcn_update_dpp(                                 \
            (int)0xFFFFFFFF, (int)(v), 0x110 | (sh), 0xF, 0xF, false);                       \
        (v) = umin32((v), _t);                                                               \
    } while (0)

// ---------- phase-1 scan: 256 blocks = (cloud, node-half). Plain stores. ----------
__global__ __launch_bounds__(T) void scan1_kernel(const float* __restrict__ gts,
                                                  const float* __restrict__ preds,
                                                  unsigned* __restrict__ bests1) {
    __shared__ float px[N], py[N], pz[N];
    __shared__ float stage[3 * N];
    __shared__ unsigned pb[2][HALF];
    const int t = threadIdx.x;
    const int cloud = blockIdx.x >> 1;
    const int nh = blockIdx.x & 1;
    const float* __restrict__ src = (cloud < 64 ? gts : preds) + (size_t)(cloud & 63) * N * 3;

    if (t < 768) ((float4*)stage)[t] = ((const float4*)src)[t];
    __syncthreads();
    px[t] = stage[3 * t]; py[t] = stage[3 * t + 1]; pz[t] = stage[3 * t + 2];
    __syncthreads();

    const int node = nh * HALF + (t & (HALF - 1));
    const int jb = (t >> 9) * HALF;
    const float ax = px[node], ay = py[node], az = pz[node];
    const v2f axv = (v2f){ax, ax}, ayv = (v2f){ay, ay}, azv = (v2f){az, az};
    unsigned best = INF32;
    #pragma unroll 8
    for (int jj = 0; jj < HALF; jj += 2) {
        int j = jb + jj;
        v2f qx = *(const v2f*)&px[j];     // ds_read_b64, j even
        v2f qy = *(const v2f*)&py[j];
        v2f qz = *(const v2f*)&pz[j];
        v2f dx = axv - qx, dy = ayv - qy, dz = azv - qz;
        v2f e = dx * dx;
        e = __builtin_elementwise_fma(dy, dy, e);
        e = __builtin_elementwise_fma(dz, dz, e);
        unsigned k0 = (__float_as_uint(e.x) & 0xFFFFF800u) | (unsigned)j;
        unsigned k1 = (__float_as_uint(e.y) & 0xFFFFF800u) | (unsigned)(j + 1);
        k0 = (j == node) ? INF32 : k0;         // suppress self
        k1 = (j + 1 == node) ? INF32 : k1;
        best = umin32(best, umin32(k0, k1));
    }
    pb[t >> 9][t & (HALF - 1)] = best;
    __syncthreads();
    if (t < HALF)
        bests1[(size_t)cloud * N + nh * HALF + t] = umin32(pb[0][t], pb[1][t]);
}

// ---------- phase-2 scan: 256 blocks; prologue rebuilds phase-1 comp labels ----------
__global__ __launch_bounds__(T) void scan2_kernel(const float* __restrict__ gts,
                                                  const float* __restrict__ preds,
                                                  const unsigned* __restrict__ bests1,
                                                  unsigned* __restrict__ bests2) {
    __shared__ float px[N], py[N], pz[N];
    __shared__ float stage[3 * N];
    __shared__ unsigned cw[N];       // comp label per node (post phase-1)
    __shared__ unsigned parent[N];
    __shared__ unsigned pb[2][HALF];
    const int t = threadIdx.x;
    const int cloud = blockIdx.x >> 1;
    const int nh = blockIdx.x & 1;
    const float* __restrict__ src = (cloud < 64 ? gts : preds) + (size_t)(cloud & 63) * N * 3;

    if (t < 768) ((float4*)stage)[t] = ((const float4*)src)[t];
    __syncthreads();
    px[t] = stage[3 * t]; py[t] = stage[3 * t + 1]; pz[t] = stage[3 * t + 2];
    // merge-1 replay (labels only, no deaths): hook parent[t] = NN(t), min-rule walk
    parent[t] = bests1[(size_t)cloud * N + t] & 0x3FFu;
    __syncthreads();
    {
        unsigned r = walk_root(parent, (unsigned)t);
        parent[t] = r;
        cw[t] = r;
    }
    __syncthreads();

    const int node = nh * HALF + (t & (HALF - 1));
    const int jb = (t >> 9) * HALF;
    const unsigned c0 = cw[node];
    const float ax = px[node], ay = py[node], az = pz[node];
    const v2f axv = (v2f){ax, ax}, ayv = (v2f){ay, ay}, azv = (v2f){az, az};
    unsigned best = INF32;
    #pragma unroll 8
    for (int jj = 0; jj < HALF; jj += 2) {
        int j = jb + jj;
        v2f qx = *(const v2f*)&px[j];
        v2f qy = *(const v2f*)&py[j];
        v2f qz = *(const v2f*)&pz[j];
        uint2 cj = *(const uint2*)&cw[j];
        v2f dx = axv - qx, dy = ayv - qy, dz = azv - qz;
        v2f e = dx * dx;
        e = __builtin_elementwise_fma(dy, dy, e);
        e = __builtin_elementwise_fma(dz, dz, e);
        unsigned k0 = (__float_as_uint(e.x) & 0xFFFFF800u) | (unsigned)j;
        unsigned k1 = (__float_as_uint(e.y) & 0xFFFFF800u) | (unsigned)(j + 1);
        k0 = (cj.x == c0) ? INF32 : k0;        // suppress same-component (incl. self)
        k1 = (cj.y == c0) ? INF32 : k1;
        best = umin32(best, umin32(k0, k1));
    }
    pb[t >> 9][t & (HALF - 1)] = best;
    __syncthreads();
    if (t < HALF)
        bests2[(size_t)cloud * N + nh * HALF + t] = umin32(pb[0][t], pb[1][t]);
}

// ---------- final: merges + (fallback phases) + contracted Prim + sort ----------
__global__ __launch_bounds__(T) void final_kernel(const float* __restrict__ gts,
                                                  const float* __restrict__ preds,
                                                  float* __restrict__ ws,
                                                  const unsigned* __restrict__ bests1,
                                                  const unsigned* __restrict__ bests2,
                                                  int nPre) {
    __shared__ float4 pts[N];        // x, y, z, w = comp bits
    __shared__ float4 spts[N];       // staging scratch; later comp-sorted points (Prim)
    __shared__ unsigned comp[N];
    __shared__ ull bestComp[N];      // merges: canonical best per root; Prim: segs (uint2)
    __shared__ unsigned parent[N];
    __shared__ __align__(16) unsigned pb[2][N];
    __shared__ float deaths[N];
    __shared__ int deathCount;

    const int t = threadIdx.x;
    const int blk = blockIdx.x;
    const float* __restrict__ src = (blk < 64 ? gts : preds) + (size_t)(blk & 63) * N * 3;

    // ---- stage + init ----
    {
        float* stg = (float*)&spts[0];
        if (t < 768) ((float4*)stg)[t] = ((const float4*)src)[t];
        __syncthreads();
        float x = stg[3 * t], y = stg[3 * t + 1], z = stg[3 * t + 2];
        pts[t] = make_float4(x, y, z, __uint_as_float((unsigned)t));
        comp[t] = (unsigned)t;
        parent[t] = (unsigned)t;
        deaths[t] = 0.0f;
        bestComp[t] = INF64;
    }
    if (t == 0) deathCount = 0;
    __syncthreads();

    const int n = t & (HALF - 1);
    const int h = t >> 9;
    const int n2 = n + HALF;
    const int jbase = h * HALF;
    float4 pA = pts[n], pB = pts[n2];
    const v2f pxv = (v2f){pA.x, pB.x};
    const v2f pyv = (v2f){pA.y, pB.y};
    const v2f pzv = (v2f){pA.z, pB.z};

    // ---- merge phase 1 from bests1 (every node is a root and hooks to its NN) ----
    if (nPre >= 1) {
        unsigned b1 = bests1[(size_t)blk * N + t];
        unsigned j1 = b1 & 0x3FFu;
        unsigned e1 = b1 & 0xFFFFF800u;
        parent[t] = j1;
        __syncthreads();
        {
            unsigned p = j1;
            unsigned gp = parent[p];
            bool mutual = (gp == (unsigned)t);
            bool rec = !mutual || ((unsigned)t < p);
            float dval = rec ? sqrtf(__uint_as_float(e1) + 1e-12f) : 0.0f;
            ull m = __ballot(rec);
            int cnt = __popcll(m);
            int base = 0;
            if ((t & 63) == 0 && cnt) base = atomicAdd(&deathCount, cnt);
            base = __shfl(base, 0, 64);
            if (rec) {
                int idx = base + __popcll(m & ((1ull << (t & 63)) - 1ull));
                if (idx < N - 1) deaths[idx] = dval;
            }
        }
        __syncthreads();
        {
            unsigned r = walk_root(parent, (unsigned)t);
            parent[t] = r;
            comp[t] = r;
            pts[t].w = __uint_as_float(r);
        }
        __syncthreads();
    }

    // ---- merge phase 2 from bests2 ----
    if (nPre >= 2) {
        unsigned b2 = bests2[(size_t)blk * N + t];
        if (b2 != INF32) {
            unsigned j2 = b2 & 0x3FFu, e2 = b2 & 0xFFFFF800u;
            unsigned mn = umin32((unsigned)t, j2), mx = umax32((unsigned)t, j2);
            atomicMin(&bestComp[comp[t]], ((ull)e2 << 20) | (ull)((mn << 10) | mx));
        }
        __syncthreads();
        const unsigned c = (unsigned)t;
        const bool isRoot = (parent[c] == c);
        {
            ull bc = bestComp[c];
            if (isRoot && bc != INF64) {
                unsigned mn = (unsigned)((bc >> 10) & 0x3FFu);
                unsigned mx = (unsigned)(bc & 0x3FFu);
                unsigned cm = comp[mn];
                parent[c] = (cm == c) ? comp[mx] : cm;
            }
        }
        __syncthreads();
        {
            bool rec = false;
            float dval = 0.0f;
            unsigned p = parent[c];
            if (isRoot && p != c) {
                unsigned gp = parent[p];
                bool mutual = (gp == c);
                rec = !mutual || (c < p);
                if (rec) dval = sqrtf(__uint_as_float((unsigned)(bestComp[c] >> 20)) + 1e-12f);
            }
            ull m = __ballot(rec);
            int cnt = __popcll(m);
            int base = 0;
            if ((t & 63) == 0 && cnt) base = atomicAdd(&deathCount, cnt);
            base = __shfl(base, 0, 64);
            if (rec) {
                int idx = base + __popcll(m & ((1ull << (t & 63)) - 1ull));
                if (idx < N - 1) deaths[idx] = dval;
            }
        }
        __syncthreads();
        {
            unsigned r = walk_root(parent, c);
            parent[t] = r;
            unsigned nc = walk_root(parent, comp[t]);
            comp[t] = nc;
            pts[t].w = __uint_as_float(nc);
            bestComp[t] = INF64;
        }
        __syncthreads();
    }

    // ---- in-kernel Boruvka phases (fallback path / adversarial data) ----
    int phase = nPre;
    while (N - deathCount > SWITCH && phase < PHASE_CAP) {
        const unsigned c0 = comp[n], c1 = comp[n2];
        unsigned best0 = INF32, best1 = INF32;
        #pragma unroll 8
        for (int jj = 0; jj < HALF; ++jj) {
            int j = jbase + jj;
            float4 pj = pts[j];
            unsigned cj = __float_as_uint(pj.w);
            v2f dx = pxv - (v2f){pj.x, pj.x};
            v2f dy = pyv - (v2f){pj.y, pj.y};
            v2f dz = pzv - (v2f){pj.z, pj.z};
            v2f e = dx * dx;
            e = __builtin_elementwise_fma(dy, dy, e);
            e = __builtin_elementwise_fma(dz, dz, e);
            unsigned k0 = (__float_as_uint(e.x) & 0xFFFFF800u) | (unsigned)j;
            unsigned k1 = (__float_as_uint(e.y) & 0xFFFFF800u) | (unsigned)j;
            k0 = (cj == c0) ? INF32 : k0;
            k1 = (cj == c1) ? INF32 : k1;
            best0 = umin32(best0, k0);
            best1 = umin32(best1, k1);
        }
        pb[h][n] = best0;
        pb[h][n2] = best1;
        __syncthreads();
        if (h == 0) {
            #pragma unroll
            for (int s = 0; s < 2; ++s) {
                int m = s == 0 ? n : n2;
                unsigned fb = umin32(pb[0][m], pb[1][m]);
                if (fb != INF32) {
                    unsigned j = fb & 0x3FFu, e = fb & 0xFFFFF800u;
                    unsigned mn = umin32((unsigned)m, j), mx = umax32((unsigned)m, j);
                    ull key = ((ull)e << 20) | (ull)((mn << 10) | mx);
                    if (phase == 0) bestComp[m] = key;
                    else atomicMin(&bestComp[comp[m]], key);
                }
            }
        }
        __syncthreads();
        const unsigned c = (unsigned)t;
        const bool isRoot = (parent[c] == c);
        {
            ull bc = bestComp[c];
            if (isRoot && bc != INF64) {
                unsigned mn = (unsigned)((bc >> 10) & 0x3FFu);
                unsigned mx = (unsigned)(bc & 0x3FFu);
                unsigned cm = comp[mn];
                parent[c] = (cm == c) ? comp[mx] : cm;
            }
        }
        __syncthreads();
        {
            bool rec = false;
            float dval = 0.0f;
            unsigned p = parent[c];
            if (isRoot && p != c) {
                unsigned gp = parent[p];
                bool mutual = (gp == c);
                rec = !mutual || (c < p);
                if (rec) dval = sqrtf(__uint_as_float((unsigned)(bestComp[c] >> 20)) + 1e-12f);
            }
            ull m = __ballot(rec);
            int cnt = __popcll(m);
            int base = 0;
            if ((t & 63) == 0 && cnt) base = atomicAdd(&deathCount, cnt);
            base = __shfl(base, 0, 64);
            if (rec) {
                int idx = base + __popcll(m & ((1ull << (t & 63)) - 1ull));
                if (idx < N - 1) deaths[idx] = dval;
            }
        }
        __syncthreads();
        {
            unsigned r = walk_root(parent, c);
            parent[t] = r;
            unsigned nc = walk_root(parent, comp[t]);
            comp[t] = nc;
            pts[t].w = __uint_as_float(nc);
            bestComp[t] = INF64;
        }
        __syncthreads();
        ++phase;
    }

    // ================= Contracted Prim on remaining comps =================
    // Node-pair packed: 512 working threads (waves 0-7), thread t owns sorted
    // positions t and t+512 in v2f lanes; waves 8-15 only hit the barrier.
    const int dcbase = deathCount;
    const int comps = N - dcbase;
    if (comps > 1) {
        unsigned* sk = &pb[0][0];
        unsigned* wavemin = &pb[1][0];   // double-buffered: [ (step&1)*8 + wid ]
        uint2* segs = (uint2*)&bestComp[0];
        sk[t] = (comp[t] << 10) | (unsigned)t;
        __syncthreads();
        for (int k = 2; k <= N; k <<= 1) {
            for (int j = k >> 1; j > 0; j >>= 1) {
                int ixj = t ^ j;
                if (ixj > t) {
                    unsigned a = sk[t], cc = sk[ixj];
                    bool up = ((t & k) == 0);
                    if ((a > cc) == up) { sk[t] = cc; sk[ixj] = a; }
                }
                __syncthreads();
            }
        }
        {
            unsigned key = sk[t];
            unsigned cme = key >> 10;
            spts[t] = pts[key & 0x3FFu];
            if (t == 0 || (sk[t - 1] >> 10) != cme) segs[cme].x = (unsigned)t;
            if (t == N - 1 || (sk[t + 1] >> 10) != cme) segs[cme].y = (unsigned)t + 1;
        }
        __syncthreads();

        const int lane = t & 63;
        const int wid = t >> 6;              // working wids: 0..7
        unsigned c_cur = comp[0];
        v2f pxv2 = (v2f){0.f, 0.f}, pyv2 = pxv2, pzv2 = pxv2;
        unsigned myc0 = 0, myc1 = 0, md0 = INF32, md1 = INF32;
        if (t < HALF) {
            float4 q0 = spts[t], q1 = spts[t + HALF];
            myc0 = sk[t] >> 10;
            myc1 = sk[t + HALF] >> 10;
            pxv2 = (v2f){q0.x, q1.x};
            pyv2 = (v2f){q0.y, q1.y};
            pzv2 = (v2f){q0.z, q1.z};
            if (myc0 == c_cur) pxv2.x = INFINITY;   // in-tree poison
            if (myc1 == c_cur) pxv2.y = INFINITY;
        }

        for (int step = 0; step < comps - 1; ++step) {
            if (t < HALF) {
                uint2 sg = segs[c_cur];          // ds_read_b64, uniform -> broadcast
                for (int jj = (int)sg.x; jj < (int)sg.y; ++jj) {
                    float4 qq = spts[jj];        // one b128 serves both nodes
                    v2f dx = pxv2 - (v2f){qq.x, qq.x};
                    v2f dy = pyv2 - (v2f){qq.y, qq.y};
                    v2f dz = pzv2 - (v2f){qq.z, qq.z};
                    v2f e = dx * dx;
                    e = __builtin_elementwise_fma(dy, dy, e);
                    e = __builtin_elementwise_fma(dz, dz, e);
                    md0 = umin32(md0, (__float_as_uint(e.x) & 0xFFFFFC00u) | myc0);
                    md1 = umin32(md1, (__float_as_uint(e.y) & 0xFFFFFC00u) | myc1);
                }
                unsigned v = umin32(md0, md1);
                DPP_MIN_SHR(v, 1);
                DPP_MIN_SHR(v, 2);
                DPP_MIN_SHR(v, 4);
                DPP_MIN_SHR(v, 8);
                unsigned r0 = (unsigned)__builtin_amdgcn_readlane((int)v, 15);
                unsigned r1 = (unsigned)__builtin_amdgcn_readlane((int)v, 31);
                unsigned r2 = (unsigned)__builtin_amdgcn_readlane((int)v, 47);
                unsigned r3 = (unsigned)__builtin_amdgcn_readlane((int)v, 63);
                if (lane == 0)
                    wavemin[(step & 1) * 8 + wid] = umin32(umin32(r0, r1), umin32(r2, r3));
            }
            __syncthreads();                     // single barrier per step (dbuf-safe)
            if (t < HALF) {
                const uint4* wmv = (const uint4*)(wavemin + (step & 1) * 8);
                uint4 u0 = wmv[0], u1 = wmv[1];
                unsigned m0 = umin32(umin32(u0.x, u0.y), umin32(u0.z, u0.w));
                unsigned m1 = umin32(umin32(u1.x, u1.y), umin32(u1.z, u1.w));
                unsigned G = umin32(m0, m1);
                c_cur = G & 0x3FFu;              // comp id directly
                if (t == 0)
                    deaths[dcbase + step] = sqrtf(__uint_as_float(G & 0xFFFFFC00u) + 1e-12f);
                if (myc0 == c_cur) { pxv2.x = INFINITY; md0 = INF32; }
                if (myc1 == c_cur) { pxv2.y = INFINITY; md1 = INF32; }
            }
        }
    }

    // ---- bitonic sort 1024 floats (1023 deaths + INF pad) ascending ----
    if (t == 0) deaths[N - 1] = INFINITY;
    __syncthreads();
    for (int k = 2; k <= N; k <<= 1) {
        for (int j = k >> 1; j > 0; j >>= 1) {
            int ixj = t ^ j;
            if (ixj > t) {
                float a = deaths[t], cc = deaths[ixj];
                bool up = ((t & k) == 0);
                if ((a > cc) == up) { deaths[t] = cc; deaths[ixj] = a; }
            }
            __syncthreads();
        }
    }

    float* dst = ws + (size_t)blk * N;
    dst[t] = (t < N - 1) ? deaths[t] : 0.0f;
}

// 64 blocks: per-batch partial sums of |deaths_a - deaths_b|
__global__ __launch_bounds__(256) void diff_partial(const float* __restrict__ ws,
                                                    float* __restrict__ partial) {
    __shared__ float red[256];
    const int t = threadIdx.x;
    const int b = blockIdx.x;
    const float* a = ws + (size_t)b * N;
    const float* c = ws + (size_t)(64 + b) * N;
    float sum = 0.0f;
    for (int i = t; i < N; i += 256)
        sum += fabsf(a[i] - c[i]);
    red[t] = sum;
    __syncthreads();
    for (int s = 128; s > 0; s >>= 1) {
        if (t < s) red[t] += red[t + s];
        __syncthreads();
    }
    if (t == 0) partial[b] = red[0];
}

__global__ __launch_bounds__(64) void diff_final(const float* __restrict__ partial,
                                                 float* __restrict__ out) {
    const int t = threadIdx.x;
    float v = partial[t];
    #pragma unroll
    for (int off = 32; off > 0; off >>= 1)
        v += __shfl_down(v, off, 64);
    if (t == 0) out[0] = v * (1.0f / 64.0f);
}

extern "C" void kernel_launch(void* const* d_in, const int* in_sizes, int n_in,
                              void* d_out, int out_size, void* d_ws, size_t ws_size,
                              hipStream_t stream) {
    const float* gts = (const float*)d_in[0];
    const float* preds = (const float*)d_in[1];
    float* ws = (float*)d_ws;                     // sorted deaths live at ws[0 .. 128*N)
    unsigned* bests1 = (unsigned*)d_ws;           // 512 KiB (overwritten by sorted deaths)
    unsigned* bests2 = bests1 + 128 * N;          // 512 KiB
    float* partial = ws + 128 * N;                // inside bests2 region (dead by then)
    const bool big = ws_size >= (size_t)(2u * 128u * N * 4u);

    if (big) {
        hipLaunchKernelGGL(scan1_kernel, dim3(256), dim3(T), 0, stream, gts, preds, bests1);
        hipLaunchKernelGGL(scan2_kernel, dim3(256), dim3(T), 0, stream, gts, preds, bests1, bests2);
        hipLaunchKernelGGL(final_kernel, dim3(128), dim3(T), 0, stream,
                           gts, preds, ws, bests1, bests2, 2);
    } else {
        hipLaunchKernelGGL(final_kernel, dim3(128), dim3(T), 0, stream,
                           gts, preds, ws, (const unsigned*)nullptr, (const unsigned*)nullptr, 0);
    }
    hipLaunchKernelGGL(diff_partial, dim3(64), dim3(256), 0, stream, ws, partial);
    hipLaunchKernelGGL(diff_final, dim3(1), dim3(64), 0, stream, partial, (float*)d_out);
}

// Round 13
// 233.364 us; speedup vs baseline: 1.0319x; 1.0319x over previous
//
#include <hip/hip_runtime.h>
#include <math.h>

#define N 1024
#define T 1024           // 16 waves: 4 per SIMD
#define HALF 512
#define PHASE_CAP 10
#define SWITCH 160       // switch to contracted Prim when comps <= SWITCH

typedef float v2f __attribute__((ext_vector_type(2)));
typedef unsigned long long ull;

#define INF64 0xFFFFFFFFFFFFFFFFull
#define INF32 0xFFFFFFFFu

__device__ __forceinline__ unsigned umin32(unsigned a, unsigned b) { return a < b ? a : b; }
__device__ __forceinline__ unsigned umax32(unsigned a, unsigned b) { return a > b ? a : b; }
__device__ __forceinline__ int imin32(int a, int b) { return a < b ? a : b; }

// Root walk with 2-cycle detection (keys globally distinct => cycles are exactly
// mutual pairs; root = min of the pair). Safe under concurrent parent[x] <- root(x).
__device__ __forceinline__ unsigned walk_root(const unsigned* parent, unsigned x) {
    unsigned prev = x, cur = parent[x];
    while (cur != prev) {
        unsigned nxt = parent[cur];
        if (nxt == prev) { cur = umin32(cur, prev); break; }
        prev = cur; cur = nxt;
    }
    return cur;
}

// DPP row_shr min step (row = 16 lanes), identity = 0xFFFFFFFF
#define DPP_MIN_SHR(v, sh)                                                                   \
    do {                                                                                     \
        unsigned _t = (unsigned)__builtin_amdgcn_update_dpp(                                 \
            (int)0xFFFFFFFF, (int)(v), 0x110 | (sh), 0xF, 0xF, false);                       \
        (v) = umin32((v), _t);                                                               \
    } while (0)

// ---------- phase-1 scan: 256 blocks = (cloud, node-half). Plain stores. ----------
__global__ __launch_bounds__(T) void scan1_kernel(const float* __restrict__ gts,
                                                  const float* __restrict__ preds,
                                                  unsigned* __restrict__ bests1) {
    __shared__ float px[N], py[N], pz[N];
    __shared__ float stage[3 * N];
    __shared__ unsigned pb[2][HALF];
    const int t = threadIdx.x;
    const int cloud = blockIdx.x >> 1;
    const int nh = blockIdx.x & 1;
    const float* __restrict__ src = (cloud < 64 ? gts : preds) + (size_t)(cloud & 63) * N * 3;

    if (t < 768) ((float4*)stage)[t] = ((const float4*)src)[t];
    __syncthreads();
    px[t] = stage[3 * t]; py[t] = stage[3 * t + 1]; pz[t] = stage[3 * t + 2];
    __syncthreads();

    const int node = nh * HALF + (t & (HALF - 1));
    const int jb = (t >> 9) * HALF;
    const float ax = px[node], ay = py[node], az = pz[node];
    const v2f axv = (v2f){ax, ax}, ayv = (v2f){ay, ay}, azv = (v2f){az, az};
    unsigned best = INF32;
    #pragma unroll 8
    for (int jj = 0; jj < HALF; jj += 2) {
        int j = jb + jj;
        v2f qx = *(const v2f*)&px[j];     // ds_read_b64, j even
        v2f qy = *(const v2f*)&py[j];
        v2f qz = *(const v2f*)&pz[j];
        v2f dx = axv - qx, dy = ayv - qy, dz = azv - qz;
        v2f e = dx * dx;
        e = __builtin_elementwise_fma(dy, dy, e);
        e = __builtin_elementwise_fma(dz, dz, e);
        unsigned k0 = (__float_as_uint(e.x) & 0xFFFFF800u) | (unsigned)j;
        unsigned k1 = (__float_as_uint(e.y) & 0xFFFFF800u) | (unsigned)(j + 1);
        k0 = (j == node) ? INF32 : k0;         // suppress self
        k1 = (j + 1 == node) ? INF32 : k1;
        best = umin32(best, umin32(k0, k1));
    }
    pb[t >> 9][t & (HALF - 1)] = best;
    __syncthreads();
    if (t < HALF)
        bests1[(size_t)cloud * N + nh * HALF + t] = umin32(pb[0][t], pb[1][t]);
}

// ---------- phase-2 scan: 256 blocks; prologue rebuilds phase-1 comp labels ----------
__global__ __launch_bounds__(T) void scan2_kernel(const float* __restrict__ gts,
                                                  const float* __restrict__ preds,
                                                  const unsigned* __restrict__ bests1,
                                                  unsigned* __restrict__ bests2) {
    __shared__ float px[N], py[N], pz[N];
    __shared__ float stage[3 * N];
    __shared__ unsigned cw[N];       // comp label per node (post phase-1)
    __shared__ unsigned parent[N];
    __shared__ unsigned pb[2][HALF];
    const int t = threadIdx.x;
    const int cloud = blockIdx.x >> 1;
    const int nh = blockIdx.x & 1;
    const float* __restrict__ src = (cloud < 64 ? gts : preds) + (size_t)(cloud & 63) * N * 3;

    if (t < 768) ((float4*)stage)[t] = ((const float4*)src)[t];
    __syncthreads();
    px[t] = stage[3 * t]; py[t] = stage[3 * t + 1]; pz[t] = stage[3 * t + 2];
    // merge-1 replay (labels only, no deaths): hook parent[t] = NN(t), min-rule walk
    parent[t] = bests1[(size_t)cloud * N + t] & 0x3FFu;
    __syncthreads();
    {
        unsigned r = walk_root(parent, (unsigned)t);
        parent[t] = r;
        cw[t] = r;
    }
    __syncthreads();

    const int node = nh * HALF + (t & (HALF - 1));
    const int jb = (t >> 9) * HALF;
    const unsigned c0 = cw[node];
    const float ax = px[node], ay = py[node], az = pz[node];
    const v2f axv = (v2f){ax, ax}, ayv = (v2f){ay, ay}, azv = (v2f){az, az};
    unsigned best = INF32;
    #pragma unroll 8
    for (int jj = 0; jj < HALF; jj += 2) {
        int j = jb + jj;
        v2f qx = *(const v2f*)&px[j];
        v2f qy = *(const v2f*)&py[j];
        v2f qz = *(const v2f*)&pz[j];
        uint2 cj = *(const uint2*)&cw[j];
        v2f dx = axv - qx, dy = ayv - qy, dz = azv - qz;
        v2f e = dx * dx;
        e = __builtin_elementwise_fma(dy, dy, e);
        e = __builtin_elementwise_fma(dz, dz, e);
        unsigned k0 = (__float_as_uint(e.x) & 0xFFFFF800u) | (unsigned)j;
        unsigned k1 = (__float_as_uint(e.y) & 0xFFFFF800u) | (unsigned)(j + 1);
        k0 = (cj.x == c0) ? INF32 : k0;        // suppress same-component (incl. self)
        k1 = (cj.y == c0) ? INF32 : k1;
        best = umin32(best, umin32(k0, k1));
    }
    pb[t >> 9][t & (HALF - 1)] = best;
    __syncthreads();
    if (t < HALF)
        bests2[(size_t)cloud * N + nh * HALF + t] = umin32(pb[0][t], pb[1][t]);
}

// ---------- final: merges + (fallback phases) + contracted Prim + sort ----------
__global__ __launch_bounds__(T) void final_kernel(const float* __restrict__ gts,
                                                  const float* __restrict__ preds,
                                                  float* __restrict__ ws,
                                                  const unsigned* __restrict__ bests1,
                                                  const unsigned* __restrict__ bests2,
                                                  int nPre) {
    __shared__ float4 pts[N];        // x, y, z, w = comp bits
    __shared__ float4 spts[N];       // staging scratch; later comp-sorted points (Prim)
    __shared__ unsigned comp[N];
    __shared__ ull bestComp[N];      // merges: canonical best per root; Prim: segs (uint2)
    __shared__ unsigned parent[N];
    __shared__ __align__(16) unsigned pb[2][N];
    __shared__ float deaths[N];
    __shared__ int deathCount;

    const int t = threadIdx.x;
    const int blk = blockIdx.x;
    const float* __restrict__ src = (blk < 64 ? gts : preds) + (size_t)(blk & 63) * N * 3;

    // ---- stage + init ----
    {
        float* stg = (float*)&spts[0];
        if (t < 768) ((float4*)stg)[t] = ((const float4*)src)[t];
        __syncthreads();
        float x = stg[3 * t], y = stg[3 * t + 1], z = stg[3 * t + 2];
        pts[t] = make_float4(x, y, z, __uint_as_float((unsigned)t));
        comp[t] = (unsigned)t;
        parent[t] = (unsigned)t;
        deaths[t] = 0.0f;
        bestComp[t] = INF64;
    }
    if (t == 0) deathCount = 0;
    __syncthreads();

    const int n = t & (HALF - 1);
    const int h = t >> 9;
    const int n2 = n + HALF;
    const int jbase = h * HALF;
    float4 pA = pts[n], pB = pts[n2];
    const v2f pxv = (v2f){pA.x, pB.x};
    const v2f pyv = (v2f){pA.y, pB.y};
    const v2f pzv = (v2f){pA.z, pB.z};

    // ---- merge phase 1 from bests1 (every node is a root and hooks to its NN) ----
    if (nPre >= 1) {
        unsigned b1 = bests1[(size_t)blk * N + t];
        unsigned j1 = b1 & 0x3FFu;
        unsigned e1 = b1 & 0xFFFFF800u;
        parent[t] = j1;
        __syncthreads();
        {
            unsigned p = j1;
            unsigned gp = parent[p];
            bool mutual = (gp == (unsigned)t);
            bool rec = !mutual || ((unsigned)t < p);
            float dval = rec ? sqrtf(__uint_as_float(e1) + 1e-12f) : 0.0f;
            ull m = __ballot(rec);
            int cnt = __popcll(m);
            int base = 0;
            if ((t & 63) == 0 && cnt) base = atomicAdd(&deathCount, cnt);
            base = __shfl(base, 0, 64);
            if (rec) {
                int idx = base + __popcll(m & ((1ull << (t & 63)) - 1ull));
                if (idx < N - 1) deaths[idx] = dval;
            }
        }
        __syncthreads();
        {
            unsigned r = walk_root(parent, (unsigned)t);
            parent[t] = r;
            comp[t] = r;
            pts[t].w = __uint_as_float(r);
        }
        __syncthreads();
    }

    // ---- merge phase 2 from bests2 ----
    if (nPre >= 2) {
        unsigned b2 = bests2[(size_t)blk * N + t];
        if (b2 != INF32) {
            unsigned j2 = b2 & 0x3FFu, e2 = b2 & 0xFFFFF800u;
            unsigned mn = umin32((unsigned)t, j2), mx = umax32((unsigned)t, j2);
            atomicMin(&bestComp[comp[t]], ((ull)e2 << 20) | (ull)((mn << 10) | mx));
        }
        __syncthreads();
        const unsigned c = (unsigned)t;
        const bool isRoot = (parent[c] == c);
        {
            ull bc = bestComp[c];
            if (isRoot && bc != INF64) {
                unsigned mn = (unsigned)((bc >> 10) & 0x3FFu);
                unsigned mx = (unsigned)(bc & 0x3FFu);
                unsigned cm = comp[mn];
                parent[c] = (cm == c) ? comp[mx] : cm;
            }
        }
        __syncthreads();
        {
            bool rec = false;
            float dval = 0.0f;
            unsigned p = parent[c];
            if (isRoot && p != c) {
                unsigned gp = parent[p];
                bool mutual = (gp == c);
                rec = !mutual || (c < p);
                if (rec) dval = sqrtf(__uint_as_float((unsigned)(bestComp[c] >> 20)) + 1e-12f);
            }
            ull m = __ballot(rec);
            int cnt = __popcll(m);
            int base = 0;
            if ((t & 63) == 0 && cnt) base = atomicAdd(&deathCount, cnt);
            base = __shfl(base, 0, 64);
            if (rec) {
                int idx = base + __popcll(m & ((1ull << (t & 63)) - 1ull));
                if (idx < N - 1) deaths[idx] = dval;
            }
        }
        __syncthreads();
        {
            unsigned r = walk_root(parent, c);
            parent[t] = r;
            unsigned nc = walk_root(parent, comp[t]);
            comp[t] = nc;
            pts[t].w = __uint_as_float(nc);
            bestComp[t] = INF64;
        }
        __syncthreads();
    }

    // ---- in-kernel Boruvka phases (fallback path / adversarial data) ----
    int phase = nPre;
    while (N - deathCount > SWITCH && phase < PHASE_CAP) {
        const unsigned c0 = comp[n], c1 = comp[n2];
        unsigned best0 = INF32, best1 = INF32;
        #pragma unroll 8
        for (int jj = 0; jj < HALF; ++jj) {
            int j = jbase + jj;
            float4 pj = pts[j];
            unsigned cj = __float_as_uint(pj.w);
            v2f dx = pxv - (v2f){pj.x, pj.x};
            v2f dy = pyv - (v2f){pj.y, pj.y};
            v2f dz = pzv - (v2f){pj.z, pj.z};
            v2f e = dx * dx;
            e = __builtin_elementwise_fma(dy, dy, e);
            e = __builtin_elementwise_fma(dz, dz, e);
            unsigned k0 = (__float_as_uint(e.x) & 0xFFFFF800u) | (unsigned)j;
            unsigned k1 = (__float_as_uint(e.y) & 0xFFFFF800u) | (unsigned)j;
            k0 = (cj == c0) ? INF32 : k0;
            k1 = (cj == c1) ? INF32 : k1;
            best0 = umin32(best0, k0);
            best1 = umin32(best1, k1);
        }
        pb[h][n] = best0;
        pb[h][n2] = best1;
        __syncthreads();
        if (h == 0) {
            #pragma unroll
            for (int s = 0; s < 2; ++s) {
                int m = s == 0 ? n : n2;
                unsigned fb = umin32(pb[0][m], pb[1][m]);
                if (fb != INF32) {
                    unsigned j = fb & 0x3FFu, e = fb & 0xFFFFF800u;
                    unsigned mn = umin32((unsigned)m, j), mx = umax32((unsigned)m, j);
                    ull key = ((ull)e << 20) | (ull)((mn << 10) | mx);
                    if (phase == 0) bestComp[m] = key;
                    else atomicMin(&bestComp[comp[m]], key);
                }
            }
        }
        __syncthreads();
        const unsigned c = (unsigned)t;
        const bool isRoot = (parent[c] == c);
        {
            ull bc = bestComp[c];
            if (isRoot && bc != INF64) {
                unsigned mn = (unsigned)((bc >> 10) & 0x3FFu);
                unsigned mx = (unsigned)(bc & 0x3FFu);
                unsigned cm = comp[mn];
                parent[c] = (cm == c) ? comp[mx] : cm;
            }
        }
        __syncthreads();
        {
            bool rec = false;
            float dval = 0.0f;
            unsigned p = parent[c];
            if (isRoot && p != c) {
                unsigned gp = parent[p];
                bool mutual = (gp == c);
                rec = !mutual || (c < p);
                if (rec) dval = sqrtf(__uint_as_float((unsigned)(bestComp[c] >> 20)) + 1e-12f);
            }
            ull m = __ballot(rec);
            int cnt = __popcll(m);
            int base = 0;
            if ((t & 63) == 0 && cnt) base = atomicAdd(&deathCount, cnt);
            base = __shfl(base, 0, 64);
            if (rec) {
                int idx = base + __popcll(m & ((1ull << (t & 63)) - 1ull));
                if (idx < N - 1) deaths[idx] = dval;
            }
        }
        __syncthreads();
        {
            unsigned r = walk_root(parent, c);
            parent[t] = r;
            unsigned nc = walk_root(parent, comp[t]);
            comp[t] = nc;
            pts[t].w = __uint_as_float(nc);
            bestComp[t] = INF64;
        }
        __syncthreads();
        ++phase;
    }

    // ================= Contracted Prim on remaining comps =================
    // Node-pair packed: 512 working threads (waves 0-7); member loop unroll-4
    // prefetched (clamped indices; duplicate evals harmless under min).
    const int dcbase = deathCount;
    const int comps = N - dcbase;
    if (comps > 1) {
        unsigned* sk = &pb[0][0];
        unsigned* wavemin = &pb[1][0];   // double-buffered: [ (step&1)*8 + wid ]
        uint2* segs = (uint2*)&bestComp[0];
        sk[t] = (comp[t] << 10) | (unsigned)t;
        __syncthreads();
        for (int k = 2; k <= N; k <<= 1) {
            for (int j = k >> 1; j > 0; j >>= 1) {
                int ixj = t ^ j;
                if (ixj > t) {
                    unsigned a = sk[t], cc = sk[ixj];
                    bool up = ((t & k) == 0);
                    if ((a > cc) == up) { sk[t] = cc; sk[ixj] = a; }
                }
                __syncthreads();
            }
        }
        {
            unsigned key = sk[t];
            unsigned cme = key >> 10;
            spts[t] = pts[key & 0x3FFu];
            if (t == 0 || (sk[t - 1] >> 10) != cme) segs[cme].x = (unsigned)t;
            if (t == N - 1 || (sk[t + 1] >> 10) != cme) segs[cme].y = (unsigned)t + 1;
        }
        __syncthreads();

        const int lane = t & 63;
        const int wid = t >> 6;              // working wids: 0..7
        unsigned c_cur = comp[0];
        v2f pxv2 = (v2f){0.f, 0.f}, pyv2 = pxv2, pzv2 = pxv2;
        unsigned myc0 = 0, myc1 = 0, md0 = INF32, md1 = INF32;
        if (t < HALF) {
            float4 q0 = spts[t], q1 = spts[t + HALF];
            myc0 = sk[t] >> 10;
            myc1 = sk[t + HALF] >> 10;
            pxv2 = (v2f){q0.x, q1.x};
            pyv2 = (v2f){q0.y, q1.y};
            pzv2 = (v2f){q0.z, q1.z};
            if (myc0 == c_cur) pxv2.x = INFINITY;   // in-tree poison
            if (myc1 == c_cur) pxv2.y = INFINITY;
        }

        for (int step = 0; step < comps - 1; ++step) {
            if (t < HALF) {
                uint2 sg = segs[c_cur];          // ds_read_b64, uniform -> broadcast
                const int jb = (int)sg.x, je = (int)sg.y, jl = je - 1;
                for (int base = jb; base < je; base += 4) {
                    // 4 independent b128 loads issued together (clamped; dups ok)
                    float4 q0 = spts[base];
                    float4 q1 = spts[imin32(base + 1, jl)];
                    float4 q2 = spts[imin32(base + 2, jl)];
                    float4 q3 = spts[imin32(base + 3, jl)];
                    #define RELAX(qq)                                                        \
                        {                                                                    \
                            v2f dx = pxv2 - (v2f){qq.x, qq.x};                               \
                            v2f dy = pyv2 - (v2f){qq.y, qq.y};                               \
                            v2f dz = pzv2 - (v2f){qq.z, qq.z};                               \
                            v2f e = dx * dx;                                                 \
                            e = __builtin_elementwise_fma(dy, dy, e);                        \
                            e = __builtin_elementwise_fma(dz, dz, e);                        \
                            md0 = umin32(md0, (__float_as_uint(e.x) & 0xFFFFFC00u) | myc0);  \
                            md1 = umin32(md1, (__float_as_uint(e.y) & 0xFFFFFC00u) | myc1);  \
                        }
                    RELAX(q0) RELAX(q1) RELAX(q2) RELAX(q3)
                    #undef RELAX
                }
                unsigned v = umin32(md0, md1);
                DPP_MIN_SHR(v, 1);
                DPP_MIN_SHR(v, 2);
                DPP_MIN_SHR(v, 4);
                DPP_MIN_SHR(v, 8);
                unsigned r0 = (unsigned)__builtin_amdgcn_readlane((int)v, 15);
                unsigned r1 = (unsigned)__builtin_amdgcn_readlane((int)v, 31);
                unsigned r2 = (unsigned)__builtin_amdgcn_readlane((int)v, 47);
                unsigned r3 = (unsigned)__builtin_amdgcn_readlane((int)v, 63);
                if (lane == 0)
                    wavemin[(step & 1) * 8 + wid] = umin32(umin32(r0, r1), umin32(r2, r3));
            }
            __syncthreads();                     // single barrier per step (dbuf-safe)
            if (t < HALF) {
                const uint4* wmv = (const uint4*)(wavemin + (step & 1) * 8);
                uint4 u0 = wmv[0], u1 = wmv[1];
                unsigned m0 = umin32(umin32(u0.x, u0.y), umin32(u0.z, u0.w));
                unsigned m1 = umin32(umin32(u1.x, u1.y), umin32(u1.z, u1.w));
                unsigned G = umin32(m0, m1);
                c_cur = G & 0x3FFu;              // comp id directly
                if (t == 0)
                    deaths[dcbase + step] = sqrtf(__uint_as_float(G & 0xFFFFFC00u) + 1e-12f);
                if (myc0 == c_cur) { pxv2.x = INFINITY; md0 = INF32; }
                if (myc1 == c_cur) { pxv2.y = INFINITY; md1 = INF32; }
            }
        }
    }

    // ---- bitonic sort 1024 floats (1023 deaths + INF pad) ascending ----
    if (t == 0) deaths[N - 1] = INFINITY;
    __syncthreads();
    for (int k = 2; k <= N; k <<= 1) {
        for (int j = k >> 1; j > 0; j >>= 1) {
            int ixj = t ^ j;
            if (ixj > t) {
                float a = deaths[t], cc = deaths[ixj];
                bool up = ((t & k) == 0);
                if ((a > cc) == up) { deaths[t] = cc; deaths[ixj] = a; }
            }
            __syncthreads();
        }
    }

    float* dst = ws + (size_t)blk * N;
    dst[t] = (t < N - 1) ? deaths[t] : 0.0f;
}

// Fused diff: 64 blocks; per-batch |a-b| sum -> atomicAdd into out (pre-zeroed).
__global__ __launch_bounds__(256) void diff_kernel(const float* __restrict__ ws,
                                                   float* __restrict__ out) {
    __shared__ float red[4];
    const int t = threadIdx.x;
    const int b = blockIdx.x;
    const float* a = ws + (size_t)b * N;
    const float* c = ws + (size_t)(64 + b) * N;
    float sum = 0.0f;
    for (int i = t; i < N; i += 256)
        sum += fabsf(a[i] - c[i]);
    #pragma unroll
    for (int off = 32; off > 0; off >>= 1)
        sum += __shfl_down(sum, off, 64);
    if ((t & 63) == 0) red[t >> 6] = sum;
    __syncthreads();
    if (t == 0)
        atomicAdd(out, (red[0] + red[1] + red[2] + red[3]) * (1.0f / 64.0f));
}

extern "C" void kernel_launch(void* const* d_in, const int* in_sizes, int n_in,
                              void* d_out, int out_size, void* d_ws, size_t ws_size,
                              hipStream_t stream) {
    const float* gts = (const float*)d_in[0];
    const float* preds = (const float*)d_in[1];
    float* ws = (float*)d_ws;                     // sorted deaths live at ws[0 .. 128*N)
    unsigned* bests1 = (unsigned*)d_ws;           // 512 KiB (overwritten by sorted deaths)
    unsigned* bests2 = bests1 + 128 * N;          // 512 KiB
    const bool big = ws_size >= (size_t)(2u * 128u * N * 4u);

    if (big) {
        hipLaunchKernelGGL(scan1_kernel, dim3(256), dim3(T), 0, stream, gts, preds, bests1);
        hipLaunchKernelGGL(scan2_kernel, dim3(256), dim3(T), 0, stream, gts, preds, bests1, bests2);
        hipLaunchKernelGGL(final_kernel, dim3(128), dim3(T), 0, stream,
                           gts, preds, ws, bests1, bests2, 2);
    } else {
        hipLaunchKernelGGL(final_kernel, dim3(128), dim3(T), 0, stream,
                           gts, preds, ws, (const unsigned*)nullptr, (const unsigned*)nullptr, 0);
    }
    hipMemsetAsync(d_out, 0, sizeof(float), stream);   // out accumulated via atomicAdd
    hipLaunchKernelGGL(diff_kernel, dim3(64), dim3(256), 0, stream, ws, (float*)d_out);
}